// Round 7
// baseline (161.008 us; speedup 1.0000x reference)
//
#include <hip/hip_runtime.h>
#include <cstdint>

#define E_EDGES 400000
#define N_NODES 25000
#define NG      25000          // groups of 16 edges
#define NPACK   18432          // ushorts: 17 K-tiles (17408) + 2 W1^T A-frags (1024)
#define EBLOCKS 1024           // exactly 4 blocks/CU on 256 CUs
#define ESTRIDE (EBLOCKS*4)    // 4096 waves, ~6 groups each

typedef float  f32x4  __attribute__((ext_vector_type(4)));
typedef __bf16 bf16x8 __attribute__((ext_vector_type(8)));

static __device__ __forceinline__ ushort f2bf(float f) {
    union { __bf16 b; ushort u; } c; c.b = (__bf16)f; return c.u;
}

// ---------------------------------------------------------------------------
// K_pack: W2(+b2 17th tile) -> MFMA B-frag order with kap remap; W1^T A-frags.
// Also: dst histogram (cnt).
// kap(kg,j) = j<4 ? 4kg+j : 16+4kg+(j-4)   (matches h-MFMA C layout)
// ---------------------------------------------------------------------------
__global__ void __launch_bounds__(256) k_pack(const float* __restrict__ W2,
                                              const float* __restrict__ b2,
                                              const float* __restrict__ W1,
                                              const int* __restrict__ ei,
                                              ushort* __restrict__ packed,
                                              uint* __restrict__ cnt_u) {
    int t = blockIdx.x * 256 + threadIdx.x;
    if (t < NPACK) {
        float v = 0.0f;
        if (t < 17408) {
            int j  = t & 7;
            int ln = (t >> 3) & 15;
            int kg = (t >> 7) & 3;
            int nt = (t >> 9) & 1;
            int kt = t >> 10;
            int kap = (j < 4) ? (kg * 4 + j) : (16 + kg * 4 + (j - 4));
            if (kt < 16)       v = W2[kap * 512 + kt * 32 + nt * 16 + ln];
            else if (kap < 16) v = b2[kap * 32 + nt * 16 + ln];
        } else {
            int idx  = t - 17408;
            int half = idx >> 9;
            int lane = (idx >> 3) & 63;
            int j    = idx & 7;
            int kg = lane >> 4, ln = lane & 15;
            if (kg == 0) v = W1[j * 32 + half * 16 + ln];  // A[m=ln(+16*half)][k=j]
        }
        packed[t] = f2bf(v);
    }
    if (t < E_EDGES) atomicAdd(&cnt_u[ei[E_EDGES + t]], 1u);
}

// ---------------------------------------------------------------------------
// K_edge: 16-edge groups, two independent acc chains, W2' in LDS.
// Two-level software pipeline per body u:
//   issue: ei(u+2), ea(u+1), x(u+1)  [each gets a full body to land]
//   compute: h-MFMA(ea_u) -> A-build(x_u) -> 17x2 MFMA -> atomic scatter
// Grid = 1024 blocks (4/CU resident), ~6 bodies per wave.
// ---------------------------------------------------------------------------
__global__ void __launch_bounds__(256, 4) k_edge(const float* __restrict__ ea,
                                                 const float* __restrict__ x,
                                                 const int* __restrict__ ei,
                                                 const ushort* __restrict__ packed,
                                                 const float* __restrict__ b1,
                                                 float* __restrict__ agg) {
    __shared__ alignas(16) ushort w2l[17408];
    {
        const uint4* s = (const uint4*)packed;
        uint4* d = (uint4*)w2l;
        for (int i = threadIdx.x; i < 2176; i += 256) d[i] = s[i];
    }
    __syncthreads();

    const int lane = threadIdx.x & 63;
    const int ln = lane & 15;
    const int kg = lane >> 4;
    const int wid = blockIdx.x * 4 + (threadIdx.x >> 6);

    // loop-invariant register state
    const bf16x8 aw0 = *(const bf16x8*)(packed + 17408 + (size_t)lane * 8);
    const bf16x8 aw1 = *(const bf16x8*)(packed + 17408 + 512 + (size_t)lane * 8);
    const f32x4 blo4 = *(const f32x4*)(b1 + 4 * kg);
    const f32x4 bhi4 = *(const f32x4*)(b1 + 16 + 4 * kg);

    const f32x4 z4 = {0.f, 0.f, 0.f, 0.f};
    const __bf16 zb = (__bf16)0.0f;

    // ---- pipeline state
    int g = wid;                            // wid < 4096 <= NG
    f32x4 eac0, eac1, xc0, xc1, xc2, xc3;   // current body's ea, x
    int s_nx = 0;                           // src idx for body u+1
    {
        const int s0 = ei[g * 16 + ln];
        const f32x4* ep = (const f32x4*)(ea + (size_t)(g * 16 + ln) * 8);
        eac0 = ep[0]; eac1 = ep[1];
        const f32x4* xp = (const f32x4*)(x + (size_t)s0 * 16);
        xc0 = xp[0]; xc1 = xp[1]; xc2 = xp[2]; xc3 = xp[3];
        const int g1 = g + ESTRIDE;
        if (g1 < NG) s_nx = ei[g1 * 16 + ln];
    }

    while (true) {
        const int gn = g + ESTRIDE;
        const bool pf = gn < NG;

        // ---- issue next body's ea + x, and ei two bodies ahead
        f32x4 ean0 = z4, ean1 = z4, xn0 = z4, xn1 = z4, xn2 = z4, xn3 = z4;
        int s_nx2 = 0;
        if (pf) {
            const f32x4* nep = (const f32x4*)(ea + (size_t)(gn * 16 + ln) * 8);
            ean0 = nep[0]; ean1 = nep[1];
            const f32x4* nxp = (const f32x4*)(x + (size_t)s_nx * 16);
            xn0 = nxp[0]; xn1 = nxp[1]; xn2 = nxp[2]; xn3 = nxp[3];
            const int gnn = gn + ESTRIDE;
            if (gnn < NG) s_nx2 = ei[gnn * 16 + ln];
        }
        const int4 d4 = *(const int4*)(ei + E_EDGES + g * 16 + kg * 4);

        // ---- h = relu(ea@W1 + b1) via 2 MFMAs (kg==0 lanes carry the B-frag)
        bf16x8 eb;
        if (kg == 0) {
            eb[0]=(__bf16)eac0[0]; eb[1]=(__bf16)eac0[1]; eb[2]=(__bf16)eac0[2]; eb[3]=(__bf16)eac0[3];
            eb[4]=(__bf16)eac1[0]; eb[5]=(__bf16)eac1[1]; eb[6]=(__bf16)eac1[2]; eb[7]=(__bf16)eac1[3];
        } else {
            eb[0]=zb; eb[1]=zb; eb[2]=zb; eb[3]=zb; eb[4]=zb; eb[5]=zb; eb[6]=zb; eb[7]=zb;
        }
        const f32x4 hA0 = __builtin_amdgcn_mfma_f32_16x16x32_bf16(aw0, eb, z4, 0, 0, 0);
        const f32x4 hA1 = __builtin_amdgcn_mfma_f32_16x16x32_bf16(aw1, eb, z4, 0, 0, 0);

        float h[8];
#pragma unroll
        for (int r = 0; r < 4; ++r) {
            h[r]     = fmaxf(hA0[r] + blo4[r], 0.f);
            h[4 + r] = fmaxf(hA1[r] + bhi4[r], 0.f);
        }

        float xr[16];
        xr[0]=xc0[0]; xr[1]=xc0[1]; xr[2]=xc0[2]; xr[3]=xc0[3];
        xr[4]=xc1[0]; xr[5]=xc1[1]; xr[6]=xc1[2]; xr[7]=xc1[3];
        xr[8]=xc2[0]; xr[9]=xc2[1]; xr[10]=xc2[2]; xr[11]=xc2[3];
        xr[12]=xc3[0]; xr[13]=xc3[1]; xr[14]=xc3[2]; xr[15]=xc3[3];

        f32x4 acc0 = z4, acc1 = z4;

#pragma unroll
        for (int kt = 0; kt < 16; ++kt) {
            const float xv = xr[kt];
            bf16x8 a;
#pragma unroll
            for (int j = 0; j < 8; ++j) a[j] = (__bf16)(xv * h[j]);
            const bf16x8 bf0 = *(const bf16x8*)(&w2l[(kt * 2 + 0) * 512 + lane * 8]);
            const bf16x8 bf1 = *(const bf16x8*)(&w2l[(kt * 2 + 1) * 512 + lane * 8]);
            acc0 = __builtin_amdgcn_mfma_f32_16x16x32_bf16(a, bf0, acc0, 0, 0, 0);
            acc1 = __builtin_amdgcn_mfma_f32_16x16x32_bf16(a, bf1, acc1, 0, 0, 0);
        }
        { // 17th K-tile folds b2: a[j<4] = x[4kg+j], a[j>=4] = 0
            const f32x4 xs = (kg == 0) ? xc0 : ((kg == 1) ? xc1 : ((kg == 2) ? xc2 : xc3));
            bf16x8 a;
            a[0]=(__bf16)xs[0]; a[1]=(__bf16)xs[1]; a[2]=(__bf16)xs[2]; a[3]=(__bf16)xs[3];
            a[4]=zb; a[5]=zb; a[6]=zb; a[7]=zb;
            const bf16x8 bf0 = *(const bf16x8*)(&w2l[(16 * 2 + 0) * 512 + lane * 8]);
            const bf16x8 bf1 = *(const bf16x8*)(&w2l[(16 * 2 + 1) * 512 + lane * 8]);
            acc0 = __builtin_amdgcn_mfma_f32_16x16x32_bf16(a, bf0, acc0, 0, 0, 0);
            acc1 = __builtin_amdgcn_mfma_f32_16x16x32_bf16(a, bf1, acc1, 0, 0, 0);
        }

        // ---- scatter: C row r = edge g*16 + kg*4 + r ; cols ln / 16+ln
        atomicAdd(&agg[d4.x * 32 + ln],      acc0[0]);
        atomicAdd(&agg[d4.y * 32 + ln],      acc0[1]);
        atomicAdd(&agg[d4.z * 32 + ln],      acc0[2]);
        atomicAdd(&agg[d4.w * 32 + ln],      acc0[3]);
        atomicAdd(&agg[d4.x * 32 + 16 + ln], acc1[0]);
        atomicAdd(&agg[d4.y * 32 + 16 + ln], acc1[1]);
        atomicAdd(&agg[d4.z * 32 + 16 + ln], acc1[2]);
        atomicAdd(&agg[d4.w * 32 + 16 + ln], acc1[3]);

        if (!pf) break;
        g = gn;
        eac0 = ean0; eac1 = ean1;
        xc0 = xn0; xc1 = xn1; xc2 = xn2; xc3 = xn3;
        s_nx = s_nx2;
    }
}

// ---------------------------------------------------------------------------
// K_node: fused  a = relu(agg/cnt + x@root + bias)  then  out = a@Wlin + blin
// ---------------------------------------------------------------------------
__global__ void __launch_bounds__(256) k_node(const float* __restrict__ agg,
                                              const uint* __restrict__ cnt_u,
                                              const float* __restrict__ x,
                                              const float* __restrict__ root,
                                              const float* __restrict__ bias,
                                              const float* __restrict__ Wlin,
                                              const float* __restrict__ blin,
                                              float* __restrict__ out) {
    __shared__ float al[256];
    const int n0 = blockIdx.x * 8;
    const int t = threadIdx.x;
    const int n = n0 + (t >> 5), h = t & 31;
    float a = 0.0f;
    if (n < N_NODES) {
        const float c = (float)cnt_u[n];
        float s = agg[n * 32 + h] / fmaxf(c, 1.0f) + bias[h];
        const f32x4* xp = (const f32x4*)(x + (size_t)n * 16);
        const f32x4 x0 = xp[0], x1 = xp[1], x2 = xp[2], x3 = xp[3];
        float xv[16];
        xv[0]=x0[0]; xv[1]=x0[1]; xv[2]=x0[2]; xv[3]=x0[3];
        xv[4]=x1[0]; xv[5]=x1[1]; xv[6]=x1[2]; xv[7]=x1[3];
        xv[8]=x2[0]; xv[9]=x2[1]; xv[10]=x2[2]; xv[11]=x2[3];
        xv[12]=x3[0]; xv[13]=x3[1]; xv[14]=x3[2]; xv[15]=x3[3];
#pragma unroll
        for (int i = 0; i < 16; ++i) s += xv[i] * root[i * 32 + h];
        a = fmaxf(s, 0.0f);
    }
    al[t] = a;
    __syncthreads();
    if (t < 128) {
        const int nj = n0 + (t >> 4), j = t & 15;
        if (nj < N_NODES) {
            float s = blin[j];
#pragma unroll
            for (int h2 = 0; h2 < 32; ++h2) s += al[(t >> 4) * 32 + h2] * Wlin[h2 * 16 + j];
            out[nj * 16 + j] = s;
        }
    }
}

// ---------------------------------------------------------------------------
extern "C" void kernel_launch(void* const* d_in, const int* in_sizes, int n_in,
                              void* d_out, int out_size, void* d_ws, size_t ws_size,
                              hipStream_t stream) {
    const float* x    = (const float*)d_in[0];
    const float* ea   = (const float*)d_in[1];
    const float* W1   = (const float*)d_in[2];
    const float* b1   = (const float*)d_in[3];
    const float* W2   = (const float*)d_in[4];
    const float* b2   = (const float*)d_in[5];
    const float* root = (const float*)d_in[6];
    const float* bias = (const float*)d_in[7];
    const float* Wlin = (const float*)d_in[8];
    const float* blin = (const float*)d_in[9];
    const int*   ei   = (const int*)d_in[10];
    float* out = (float*)d_out;

    char* ws = (char*)d_ws;
    float*  agg    = (float*)(ws + 0);           // 3,200,000
    uint*   cnt_u  = (uint*)(ws + 3200000);      //   100,000
    ushort* packed = (ushort*)(ws + 3300000);    //    36,864

    hipMemsetAsync(d_ws, 0, 3300000, stream);    // agg + cnt_u

    k_pack<<<1563, 256, 0, stream>>>(W2, b2, W1, ei, packed, cnt_u);
    k_edge<<<EBLOCKS, 256, 0, stream>>>(ea, x, ei, packed, b1, agg);
    k_node<<<3125, 256, 0, stream>>>(agg, cnt_u, x, root, bias, Wlin, blin, out);
}

// Round 8
// 123.802 us; speedup vs baseline: 1.3005x; 1.3005x over previous
//
#include <hip/hip_runtime.h>
#include <cstdint>

#define E_EDGES 400000
#define N_NODES 25000
#define NG      25000          // groups of 16 edges
#define NPACK   18432          // ushorts: 17 K-tiles (17408) + 2 W1^T A-frags (1024)
#define EBLOCKS 768            // 3 blocks/CU (45KB LDS each)
#define ESTRIDE (EBLOCKS*4)    // 3072 waves, grid-stride over groups

typedef float  f32x4  __attribute__((ext_vector_type(4)));
typedef __bf16 bf16x8 __attribute__((ext_vector_type(8)));

static __device__ __forceinline__ float bf2f(uint32_t u) {
    union { uint32_t u; float f; } v; v.u = u << 16; return v.f;
}
static __device__ __forceinline__ ushort f2bf(float f) {
    union { __bf16 b; ushort u; } c; c.b = (__bf16)f; return c.u;
}
static __device__ __forceinline__ uint pk2(float a, float b) {
    return (uint)f2bf(a) | ((uint)f2bf(b) << 16);
}

// ---------------------------------------------------------------------------
// K_pack: W2(+b2 17th tile) -> MFMA B-frag order with kap remap; W1^T A-frags.
// Also: dst histogram (cnt) for the CSR offsets.
// kap(kg,j) = j<4 ? 4kg+j : 16+4kg+(j-4)   (matches h-MFMA C layout)
// ---------------------------------------------------------------------------
__global__ void __launch_bounds__(256) k_pack(const float* __restrict__ W2,
                                              const float* __restrict__ b2,
                                              const float* __restrict__ W1,
                                              const int* __restrict__ ei,
                                              ushort* __restrict__ packed,
                                              uint* __restrict__ cnt_u) {
    int t = blockIdx.x * 256 + threadIdx.x;
    if (t < NPACK) {
        float v = 0.0f;
        if (t < 17408) {
            int j  = t & 7;
            int ln = (t >> 3) & 15;
            int kg = (t >> 7) & 3;
            int nt = (t >> 9) & 1;
            int kt = t >> 10;
            int kap = (j < 4) ? (kg * 4 + j) : (16 + kg * 4 + (j - 4));
            if (kt < 16)       v = W2[kap * 512 + kt * 32 + nt * 16 + ln];
            else if (kap < 16) v = b2[kap * 32 + nt * 16 + ln];
        } else {
            int idx  = t - 17408;
            int half = idx >> 9;
            int lane = (idx >> 3) & 63;
            int j    = idx & 7;
            int kg = lane >> 4, ln = lane & 15;
            if (kg == 0) v = W1[j * 32 + half * 16 + ln];  // A[m=ln(+16*half)][k=j]
        }
        packed[t] = f2bf(v);
    }
    if (t < E_EDGES) atomicAdd(&cnt_u[ei[E_EDGES + t]], 1u);
}

// ---------------------------------------------------------------------------
// K_scan: single-block exclusive scan of 25000 counts -> ofs[25001] (+ work copy)
// ---------------------------------------------------------------------------
__global__ void __launch_bounds__(1024) k_scan(const uint* __restrict__ cnt_u,
                                               uint* __restrict__ ofs,
                                               uint* __restrict__ ofs_work) {
    const int t = threadIdx.x;
    const int B = 25;                     // 1024*25 = 25600 >= 25000
    uint loc[B];
    uint s = 0;
    const int base = t * B;
#pragma unroll
    for (int k = 0; k < B; ++k) {
        int i = base + k;
        uint v = (i < N_NODES) ? cnt_u[i] : 0u;
        loc[k] = s; s += v;
    }
    const int lane = t & 63;
    uint incl = s;
#pragma unroll
    for (int off = 1; off < 64; off <<= 1) {
        uint u = __shfl_up(incl, off, 64);
        if (lane >= off) incl += u;
    }
    __shared__ uint wsum[16], wpre[16];
    const int wid = t >> 6;
    if (lane == 63) wsum[wid] = incl;
    __syncthreads();
    if (t == 0) { uint c = 0; for (int w = 0; w < 16; ++w) { wpre[w] = c; c += wsum[w]; } }
    __syncthreads();
    const uint thr_excl = incl - s + wpre[wid];
#pragma unroll
    for (int k = 0; k < B; ++k) {
        int i = base + k;
        if (i < N_NODES) { uint e = thr_excl + loc[k]; ofs[i] = e; ofs_work[i] = e; }
    }
    if (t == 1023) ofs[N_NODES] = thr_excl + s;
}

// ---------------------------------------------------------------------------
// K_edge: NO atomics on agg. Per 16-edge group:
//   h via MFMA, A'-build, 17x2 MFMA (two acc chains),
//   C tile -> LDS transpose -> bf16 -> ONE coalesced dwordx4 store per lane,
//   + CSR rank (16 predicated atomics on ofs_work, perm[r]=e).
// r4's two-level pipeline retained (ei 2 ahead, ea/x 1 ahead).
// ---------------------------------------------------------------------------
__global__ void __launch_bounds__(256) k_edge(const float* __restrict__ ea,
                                              const float* __restrict__ x,
                                              const int* __restrict__ ei,
                                              const ushort* __restrict__ packed,
                                              const float* __restrict__ b1,
                                              ushort* __restrict__ msgb,
                                              int* __restrict__ perm,
                                              uint* __restrict__ ofs_work) {
    __shared__ alignas(16) ushort w2l[17408];
    __shared__ alignas(16) float tbuf[4][16 * 40];   // per-wave transpose tile
    {
        const uint4* s = (const uint4*)packed;
        uint4* d = (uint4*)w2l;
        for (int i = threadIdx.x; i < 2176; i += 256) d[i] = s[i];
    }
    __syncthreads();

    const int lane = threadIdx.x & 63;
    const int ln = lane & 15;
    const int kg = lane >> 4;
    const int w  = threadIdx.x >> 6;
    const int wid = blockIdx.x * 4 + w;

    // loop-invariant register state
    const bf16x8 aw0 = *(const bf16x8*)(packed + 17408 + (size_t)lane * 8);
    const bf16x8 aw1 = *(const bf16x8*)(packed + 17408 + 512 + (size_t)lane * 8);
    const f32x4 blo4 = *(const f32x4*)(b1 + 4 * kg);
    const f32x4 bhi4 = *(const f32x4*)(b1 + 16 + 4 * kg);

    const f32x4 z4 = {0.f, 0.f, 0.f, 0.f};
    const __bf16 zb = (__bf16)0.0f;

    // ---- pipeline state
    int g = wid;                            // wid < 3072 <= NG
    f32x4 eac0, eac1, xc0, xc1, xc2, xc3;
    int s_nx = 0;
    {
        const int s0 = ei[g * 16 + ln];
        const f32x4* ep = (const f32x4*)(ea + (size_t)(g * 16 + ln) * 8);
        eac0 = ep[0]; eac1 = ep[1];
        const f32x4* xp = (const f32x4*)(x + (size_t)s0 * 16);
        xc0 = xp[0]; xc1 = xp[1]; xc2 = xp[2]; xc3 = xp[3];
        const int g1 = g + ESTRIDE;
        if (g1 < NG) s_nx = ei[g1 * 16 + ln];
    }

    while (true) {
        const int gn = g + ESTRIDE;
        const bool pf = gn < NG;
        const int g16 = g * 16;

        // ---- issue next body's ea + x, and ei two bodies ahead
        f32x4 ean0 = z4, ean1 = z4, xn0 = z4, xn1 = z4, xn2 = z4, xn3 = z4;
        int s_nx2 = 0;
        if (pf) {
            const f32x4* nep = (const f32x4*)(ea + (size_t)(gn * 16 + ln) * 8);
            ean0 = nep[0]; ean1 = nep[1];
            const f32x4* nxp = (const f32x4*)(x + (size_t)s_nx * 16);
            xn0 = nxp[0]; xn1 = nxp[1]; xn2 = nxp[2]; xn3 = nxp[3];
            const int gnn = gn + ESTRIDE;
            if (gnn < NG) s_nx2 = ei[gnn * 16 + ln];
        }
        const int4 d4 = *(const int4*)(ei + E_EDGES + g16 + kg * 4);

        // ---- CSR rank: one lane per edge (ln<4 across the 4 kg quartets)
        if (ln < 4) {
            const int dsel = (ln == 0) ? d4.x : ((ln == 1) ? d4.y : ((ln == 2) ? d4.z : d4.w));
            const uint r = atomicAdd(&ofs_work[dsel], 1u);
            perm[r] = g16 + kg * 4 + ln;
        }

        // ---- h = relu(ea@W1 + b1) via 2 MFMAs (kg==0 lanes carry the B-frag)
        bf16x8 eb;
        if (kg == 0) {
            eb[0]=(__bf16)eac0[0]; eb[1]=(__bf16)eac0[1]; eb[2]=(__bf16)eac0[2]; eb[3]=(__bf16)eac0[3];
            eb[4]=(__bf16)eac1[0]; eb[5]=(__bf16)eac1[1]; eb[6]=(__bf16)eac1[2]; eb[7]=(__bf16)eac1[3];
        } else {
            eb[0]=zb; eb[1]=zb; eb[2]=zb; eb[3]=zb; eb[4]=zb; eb[5]=zb; eb[6]=zb; eb[7]=zb;
        }
        const f32x4 hA0 = __builtin_amdgcn_mfma_f32_16x16x32_bf16(aw0, eb, z4, 0, 0, 0);
        const f32x4 hA1 = __builtin_amdgcn_mfma_f32_16x16x32_bf16(aw1, eb, z4, 0, 0, 0);

        float h[8];
#pragma unroll
        for (int r = 0; r < 4; ++r) {
            h[r]     = fmaxf(hA0[r] + blo4[r], 0.f);
            h[4 + r] = fmaxf(hA1[r] + bhi4[r], 0.f);
        }

        float xr[16];
        xr[0]=xc0[0]; xr[1]=xc0[1]; xr[2]=xc0[2]; xr[3]=xc0[3];
        xr[4]=xc1[0]; xr[5]=xc1[1]; xr[6]=xc1[2]; xr[7]=xc1[3];
        xr[8]=xc2[0]; xr[9]=xc2[1]; xr[10]=xc2[2]; xr[11]=xc2[3];
        xr[12]=xc3[0]; xr[13]=xc3[1]; xr[14]=xc3[2]; xr[15]=xc3[3];

        f32x4 acc0 = z4, acc1 = z4;

#pragma unroll
        for (int kt = 0; kt < 16; ++kt) {
            const float xv = xr[kt];
            bf16x8 a;
#pragma unroll
            for (int j = 0; j < 8; ++j) a[j] = (__bf16)(xv * h[j]);
            const bf16x8 bf0 = *(const bf16x8*)(&w2l[(kt * 2 + 0) * 512 + lane * 8]);
            const bf16x8 bf1 = *(const bf16x8*)(&w2l[(kt * 2 + 1) * 512 + lane * 8]);
            acc0 = __builtin_amdgcn_mfma_f32_16x16x32_bf16(a, bf0, acc0, 0, 0, 0);
            acc1 = __builtin_amdgcn_mfma_f32_16x16x32_bf16(a, bf1, acc1, 0, 0, 0);
        }
        { // 17th K-tile folds b2
            const f32x4 xs = (kg == 0) ? xc0 : ((kg == 1) ? xc1 : ((kg == 2) ? xc2 : xc3));
            bf16x8 a;
            a[0]=(__bf16)xs[0]; a[1]=(__bf16)xs[1]; a[2]=(__bf16)xs[2]; a[3]=(__bf16)xs[3];
            a[4]=zb; a[5]=zb; a[6]=zb; a[7]=zb;
            const bf16x8 bf0 = *(const bf16x8*)(&w2l[(16 * 2 + 0) * 512 + lane * 8]);
            const bf16x8 bf1 = *(const bf16x8*)(&w2l[(16 * 2 + 1) * 512 + lane * 8]);
            acc0 = __builtin_amdgcn_mfma_f32_16x16x32_bf16(a, bf0, acc0, 0, 0, 0);
            acc1 = __builtin_amdgcn_mfma_f32_16x16x32_bf16(a, bf1, acc1, 0, 0, 0);
        }

        // ---- LDS transpose: C(row=kg*4+r, col=ln)=acc0[r], col 16+ln=acc1[r]
#pragma unroll
        for (int r = 0; r < 4; ++r) {
            tbuf[w][(kg * 4 + r) * 40 + ln]      = acc0[r];
            tbuf[w][(kg * 4 + r) * 40 + 16 + ln] = acc1[r];
        }
        asm volatile("s_waitcnt lgkmcnt(0)" ::: "memory");
        {
            const int row = lane >> 2, c8 = lane & 3;
            const f32x4 lo = *(const f32x4*)&tbuf[w][row * 40 + c8 * 8];
            const f32x4 hi = *(const f32x4*)&tbuf[w][row * 40 + c8 * 8 + 4];
            uint4 uu;
            uu.x = pk2(lo[0], lo[1]); uu.y = pk2(lo[2], lo[3]);
            uu.z = pk2(hi[0], hi[1]); uu.w = pk2(hi[2], hi[3]);
            *(uint4*)(msgb + (size_t)(g16 + row) * 32 + c8 * 8) = uu;
        }

        if (!pf) break;
        g = gn;
        eac0 = ean0; eac1 = ean1;
        xc0 = xn0; xc1 = xn1; xc2 = xn2; xc3 = xn3;
        s_nx = s_nx2;
    }
}

// ---------------------------------------------------------------------------
// K_node: one wave per node. CSR gather of bf16 msg rows, mean, then fused
// relu(agg/deg + x@root + bias) @ Wlin + blin.
// lane = slot*8 + q : slot picks row-in-batch, q picks 4 output cols.
// ---------------------------------------------------------------------------
__global__ void __launch_bounds__(256) k_node(const ushort* __restrict__ msgb,
                                              const uint* __restrict__ ofs,
                                              const int* __restrict__ perm,
                                              const float* __restrict__ x,
                                              const float* __restrict__ root,
                                              const float* __restrict__ bias,
                                              const float* __restrict__ Wlin,
                                              const float* __restrict__ blin,
                                              float* __restrict__ out) {
    __shared__ float rootL[512], WlinL[512], biasL[32], blinL[16];
    __shared__ alignas(16) float aL[4][32];
    const int tid = threadIdx.x;
    rootL[tid] = root[tid]; rootL[256 + tid] = root[256 + tid];
    WlinL[tid] = Wlin[tid]; WlinL[256 + tid] = Wlin[256 + tid];
    if (tid < 32) biasL[tid] = bias[tid];
    if (tid < 16) blinL[tid] = blin[tid];
    __syncthreads();

    const int w = tid >> 6, lane = tid & 63;
    const int n = blockIdx.x * 4 + w;
    if (n >= N_NODES) return;
    const int slot = lane >> 3, q = lane & 7;

    const uint r0 = ofs[n], r1 = ofs[n + 1];
    const int deg = (int)(r1 - r0);

    float s0 = 0.f, s1 = 0.f, s2 = 0.f, s3 = 0.f;
    for (int base = 0; base < deg; base += 64) {
        const int m = min(64, deg - base);
        int e_l = 0;
        if (lane < m) e_l = perm[r0 + base + lane];
        const int nb = (m + 7) >> 3;
        for (int b = 0; b < nb; ++b) {
            const int idx = b * 8 + slot;
            const int e = __shfl(e_l, idx);
            if (idx < m) {
                const uint2 u = *(const uint2*)(msgb + (size_t)e * 32 + q * 4);
                s0 += bf2f(u.x & 0xffffu); s1 += bf2f(u.x >> 16);
                s2 += bf2f(u.y & 0xffffu); s3 += bf2f(u.y >> 16);
            }
        }
    }
    // reduce over slot bits (8,16,32)
#pragma unroll
    for (int msk = 8; msk < 64; msk <<= 1) {
        s0 += __shfl_xor(s0, msk); s1 += __shfl_xor(s1, msk);
        s2 += __shfl_xor(s2, msk); s3 += __shfl_xor(s3, msk);
    }

    const float inv = 1.0f / fmaxf((float)deg, 1.0f);
    float a0 = s0 * inv + biasL[q * 4 + 0];
    float a1 = s1 * inv + biasL[q * 4 + 1];
    float a2 = s2 * inv + biasL[q * 4 + 2];
    float a3 = s3 * inv + biasL[q * 4 + 3];

    const float xi = (lane < 16) ? x[n * 16 + lane] : 0.0f;
#pragma unroll
    for (int i = 0; i < 16; ++i) {
        const float xv = __shfl(xi, i);
        a0 += xv * rootL[i * 32 + q * 4 + 0];
        a1 += xv * rootL[i * 32 + q * 4 + 1];
        a2 += xv * rootL[i * 32 + q * 4 + 2];
        a3 += xv * rootL[i * 32 + q * 4 + 3];
    }
    a0 = fmaxf(a0, 0.f); a1 = fmaxf(a1, 0.f); a2 = fmaxf(a2, 0.f); a3 = fmaxf(a3, 0.f);

    if (slot == 0) {
        f32x4 av = {a0, a1, a2, a3};
        *(f32x4*)&aL[w][q * 4] = av;
    }
    asm volatile("s_waitcnt lgkmcnt(0)" ::: "memory");
    if (lane < 16) {
        float o = blinL[lane];
#pragma unroll
        for (int hh = 0; hh < 32; ++hh) o += aL[w][hh] * WlinL[hh * 16 + lane];
        out[n * 16 + lane] = o;
    }
}

// ---------------------------------------------------------------------------
extern "C" void kernel_launch(void* const* d_in, const int* in_sizes, int n_in,
                              void* d_out, int out_size, void* d_ws, size_t ws_size,
                              hipStream_t stream) {
    const float* x    = (const float*)d_in[0];
    const float* ea   = (const float*)d_in[1];
    const float* W1   = (const float*)d_in[2];
    const float* b1   = (const float*)d_in[3];
    const float* W2   = (const float*)d_in[4];
    const float* b2   = (const float*)d_in[5];
    const float* root = (const float*)d_in[6];
    const float* bias = (const float*)d_in[7];
    const float* Wlin = (const float*)d_in[8];
    const float* blin = (const float*)d_in[9];
    const int*   ei   = (const int*)d_in[10];
    float* out = (float*)d_out;

    char* ws = (char*)d_ws;
    uint*   cnt_u    = (uint*)(ws + 0);            //   100,000
    uint*   ofs      = (uint*)(ws + 100000);       //   100,004
    uint*   ofs_work = (uint*)(ws + 200016);       //   100,000
    ushort* packed   = (ushort*)(ws + 300032);     //    36,864
    int*    perm     = (int*)(ws + 336896);        // 1,600,000
    ushort* msgb     = (ushort*)(ws + 1936896);    // 25,600,000  (total ~27.5 MB)

    hipMemsetAsync(cnt_u, 0, 100000, stream);

    k_pack<<<1563, 256, 0, stream>>>(W2, b2, W1, ei, packed, cnt_u);
    k_scan<<<1, 1024, 0, stream>>>(cnt_u, ofs, ofs_work);
    k_edge<<<EBLOCKS, 256, 0, stream>>>(ea, x, ei, packed, b1, msgb, perm, ofs_work);
    k_node<<<(N_NODES + 3) / 4, 256, 0, stream>>>(msgb, ofs, perm, x, root, bias, Wlin, blin, out);
}